// Round 1
// baseline (797.449 us; speedup 1.0000x reference)
//
#include <hip/hip_runtime.h>
#include <cstdint>
#include <cstddef>

#define N_NODES 20000
#define F_IN    2000
#define H_DIM   128
#define L_DIM   15
#define K_PAD   2048      // F padded for BK
#define M_PAD   20096     // 157 * 128
#define N1      512       // 4 hops * 128
#define BM      128
#define BN      128
#define BK      32

typedef __attribute__((ext_vector_type(4))) float f32x4;
typedef __attribute__((ext_vector_type(8))) short s16x8;

__device__ __forceinline__ unsigned short f2bf(float f) {
  unsigned int u = __float_as_uint(f);
  u += 0x7fff + ((u >> 16) & 1);   // RNE
  return (unsigned short)(u >> 16);
}

// ---- x (fp32 [20000][2000]) -> bf16 padded [20096][2048], zero-filled pad ----
__global__ __launch_bounds__(256) void k_cvt_x(const float* __restrict__ x,
                                               unsigned short* __restrict__ xb) {
  unsigned int i = blockIdx.x * 256u + threadIdx.x;
  unsigned int row = i >> 11, col = i & (K_PAD - 1);
  float v = 0.f;
  if (row < N_NODES && col < F_IN) v = x[(size_t)row * F_IN + col];
  xb[i] = f2bf(v);
}

// ---- W1 [8000][128] -> bf16 B^T layout [512][2048]: bt[hop*128+c][k] = W1[hop*2000+k][c] ----
__global__ __launch_bounds__(256) void k_cvt_w1(const float* __restrict__ W1,
                                                unsigned short* __restrict__ bt) {
  unsigned int i = blockIdx.x * 256u + threadIdx.x;
  unsigned int n = i >> 11, k = i & (K_PAD - 1);
  float v = 0.f;
  if (k < F_IN) {
    unsigned int hop = n >> 7, c = n & 127;
    v = W1[(size_t)(hop * F_IN + k) * H_DIM + c];
  }
  bt[i] = f2bf(v);
}

// ---- Y[20000][512] = xb @ w1r^T  (m97-style bf16 MFMA GEMM) ----
__global__ __launch_bounds__(256) void k_gemm1(const unsigned short* __restrict__ A,
                                               const unsigned short* __restrict__ B,
                                               float* __restrict__ C) {
  __shared__ unsigned short As[BM * BK];
  __shared__ unsigned short Bs[BN * BK];
  const int tid  = threadIdx.x;
  const int lane = tid & 63;
  const int wave = tid >> 6;
  const int wm = (wave >> 1) * 64;
  const int wn = (wave & 1) * 64;
  const int rowA0 = blockIdx.x * BM;
  const int colB0 = blockIdx.y * BN;
  const int quad = lane >> 4;
  const int l15  = lane & 15;
  f32x4 acc[4][4] = {};

  for (int kt = 0; kt < K_PAD; kt += BK) {
#pragma unroll
    for (int r = 0; r < 2; ++r) {
      int c = r * 256 + tid;
      int row = c >> 2;
      int kc = (c & 3) * 8;
      const unsigned short* ga = A + (size_t)(rowA0 + row) * K_PAD + kt + kc;
      __builtin_amdgcn_global_load_lds((const __attribute__((address_space(1))) void*)ga,
                                       (__attribute__((address_space(3))) void*)(As + c * 8),
                                       16, 0, 0);
      const unsigned short* gb = B + (size_t)(colB0 + row) * K_PAD + kt + kc;
      __builtin_amdgcn_global_load_lds((const __attribute__((address_space(1))) void*)gb,
                                       (__attribute__((address_space(3))) void*)(Bs + c * 8),
                                       16, 0, 0);
    }
    __syncthreads();
    s16x8 af[4], bf[4];
#pragma unroll
    for (int i = 0; i < 4; ++i)
      af[i] = *(const s16x8*)(As + (wm + i * 16 + l15) * BK + quad * 8);
#pragma unroll
    for (int j = 0; j < 4; ++j)
      bf[j] = *(const s16x8*)(Bs + (wn + j * 16 + l15) * BK + quad * 8);
#pragma unroll
    for (int i = 0; i < 4; ++i)
#pragma unroll
      for (int j = 0; j < 4; ++j)
        acc[i][j] = __builtin_amdgcn_mfma_f32_16x16x32_bf16(af[i], bf[j], acc[i][j], 0, 0, 0);
    __syncthreads();
  }

#pragma unroll
  for (int i = 0; i < 4; ++i) {
    int row0 = rowA0 + wm + i * 16 + quad * 4;
#pragma unroll
    for (int j = 0; j < 4; ++j) {
      int col = colB0 + wn + j * 16 + l15;
#pragma unroll
      for (int r = 0; r < 4; ++r) {
        int row = row0 + r;
        if (row < N_NODES) C[(size_t)row * N1 + col] = acc[i][j][r];
      }
    }
  }
}

// ---- CSR build: histogram, scan, scatter ----
__global__ __launch_bounds__(256) void k_hist(const int* __restrict__ dst,
                                              int* __restrict__ deg, int E) {
  int e = blockIdx.x * 256 + threadIdx.x;
  if (e < E) atomicAdd(&deg[dst[e]], 1);
}

__global__ __launch_bounds__(1024) void k_scan(const int* __restrict__ deg,
                                               int* __restrict__ rowStart,
                                               int* __restrict__ cursor) {
  __shared__ int sums[1024];
  const int t = threadIdx.x;
  const int chunk = (N_NODES + 1023) / 1024;  // 20
  int lo = t * chunk;
  int hi = lo + chunk; if (hi > N_NODES) hi = N_NODES;
  int s = 0;
  for (int i = lo; i < hi; ++i) s += deg[i];
  sums[t] = s;
  __syncthreads();
  for (int off = 1; off < 1024; off <<= 1) {
    int v = sums[t];
    int u = (t >= off) ? sums[t - off] : 0;
    __syncthreads();
    sums[t] = v + u;
    __syncthreads();
  }
  int run = sums[t] - s;  // exclusive prefix
  for (int i = lo; i < hi; ++i) {
    rowStart[i] = run; cursor[i] = run; run += deg[i];
  }
  if (t == 1023) rowStart[N_NODES] = run;
}

__global__ __launch_bounds__(256) void k_scatter(const int* __restrict__ src,
                                                 const int* __restrict__ dst,
                                                 const float* __restrict__ w,
                                                 int* cursor,
                                                 int* __restrict__ srcS,
                                                 float* __restrict__ wS, int E) {
  int e = blockIdx.x * 256 + threadIdx.x;
  if (e >= E) return;
  int p = atomicAdd(&cursor[dst[e]], 1);
  srcS[p] = src[e];
  wS[p] = w[e];
}

// ---- pull-propagation on 128-wide features: out[d] = addv[d] + sum w*in[src] ----
__global__ __launch_bounds__(256) void k_prop128(const int* __restrict__ rowStart,
    const int* __restrict__ srcS, const float* __restrict__ wS,
    const float* __restrict__ in, int inStride, int inOff,
    const float* __restrict__ addv, int addStride, int addOff,
    float* __restrict__ out) {
  const int lane = threadIdx.x & 63;
  const int d = blockIdx.x * 4 + (threadIdx.x >> 6);
  if (d >= N_NODES) return;
  const int s0 = rowStart[d], s1 = rowStart[d + 1];
  float a0 = 0.f, a1 = 0.f;
  for (int j = s0; j < s1; ++j) {
    const int s = srcS[j];
    const float w = wS[j];
    const float* ip = in + (size_t)s * inStride + inOff;
    a0 = fmaf(w, ip[lane], a0);
    a1 = fmaf(w, ip[lane + 64], a1);
  }
  const float* ap = addv + (size_t)d * addStride + addOff;
  out[(size_t)d * H_DIM + lane]      = ap[lane] + a0;
  out[(size_t)d * H_DIM + lane + 64] = ap[lane + 64] + a1;
}

// ---- BN(inference) + ReLU, also adds b1 (TAGConv bias) ----
__global__ __launch_bounds__(256) void k_bnrelu(const float* __restrict__ P,
    const float* __restrict__ b1, const float* __restrict__ gamma,
    const float* __restrict__ beta, const float* __restrict__ mean,
    const float* __restrict__ var, float* __restrict__ Hout) {
  unsigned int i = blockIdx.x * 256u + threadIdx.x;
  if (i >= (unsigned)N_NODES * H_DIM) return;
  int c = i & 127;
  float v = P[i] + b1[c];
  v = (v - mean[c]) * rsqrtf(var[c] + 1e-3f) * gamma[c] + beta[c];
  Hout[i] = v > 0.f ? v : 0.f;
}

// ---- Y2[20000][60] = H @ W2 (4 hop-blocks of [128][15]); tiny fp32 GEMM ----
__global__ __launch_bounds__(256) void k_gemm2(const float* __restrict__ Hh,
                                               const float* __restrict__ W2,
                                               float* __restrict__ Y2) {
  __shared__ float w2s[512 * 15];
  for (int i = threadIdx.x; i < 512 * 15; i += 256) w2s[i] = W2[i];
  __syncthreads();
  const int c = threadIdx.x & 63;
  const int d = blockIdx.x * 4 + (threadIdx.x >> 6);
  if (c >= 60 || d >= N_NODES) return;
  const int hop = c / 15, j = c % 15;
  const float* hr = Hh + (size_t)d * H_DIM;
  float acc = 0.f;
#pragma unroll 4
  for (int k = 0; k < H_DIM; ++k)
    acc = fmaf(hr[k], w2s[(hop * H_DIM + k) * 15 + j], acc);
  Y2[(size_t)d * 60 + c] = acc;
}

// ---- pull-propagation on 15-wide features ----
__global__ __launch_bounds__(256) void k_prop15(const int* __restrict__ rowStart,
    const int* __restrict__ srcS, const float* __restrict__ wS,
    const float* __restrict__ in, int inStride, int inOff,
    const float* __restrict__ addv, int addStride, int addOff,
    const float* __restrict__ bias, float* __restrict__ out) {
  const int f = threadIdx.x & 15;
  const int d = blockIdx.x * 16 + (threadIdx.x >> 4);
  if (d >= N_NODES || f >= 15) return;
  float acc = 0.f;
  const int s0 = rowStart[d], s1 = rowStart[d + 1];
  for (int j = s0; j < s1; ++j)
    acc = fmaf(wS[j], in[(size_t)srcS[j] * inStride + inOff + f], acc);
  float b = bias ? bias[f] : 0.f;
  out[(size_t)d * 15 + f] = addv[(size_t)d * addStride + addOff + f] + acc + b;
}

extern "C" void kernel_launch(void* const* d_in, const int* in_sizes, int n_in,
                              void* d_out, int out_size, void* d_ws, size_t ws_size,
                              hipStream_t stream) {
  const float* x     = (const float*)d_in[0];
  const int*   esrc  = (const int*)d_in[1];
  const int*   edst  = (const int*)d_in[2];
  const float* ew    = (const float*)d_in[3];
  const float* W1    = (const float*)d_in[4];
  const float* b1    = (const float*)d_in[5];
  const float* gamma = (const float*)d_in[6];
  const float* beta  = (const float*)d_in[7];
  const float* mmean = (const float*)d_in[8];
  const float* mvar  = (const float*)d_in[9];
  const float* W2    = (const float*)d_in[10];
  const float* b2    = (const float*)d_in[11];
  const int E = in_sizes[1];
  char* ws = (char*)d_ws;

  // persistent region
  unsigned short* xb  = (unsigned short*)(ws);                 // 82,313,216 B
  unsigned short* w1r = (unsigned short*)(ws + 82313216);      //  2,097,152 B
  float* Y        = (float*)(ws + 84410368);                   // 40,960,000 B
  int*   deg      = (int*)(ws + 125370368);                    //     80,128 B
  int*   rowStart = (int*)(ws + 125450496);                    //     80,128 B
  int*   cursor   = (int*)(ws + 125530624);                    //     80,128 B
  int*   srcS     = (int*)(ws + 125610752);                    //  2,560,000 B
  float* wS       = (float*)(ws + 128170752);                  //  2,560,000 B
  // aliases over xb region (xb dead after k_gemm1)
  float* P   = (float*)(ws);                                   // 10,240,000 B
  float* Q   = (float*)(ws + 10240000);                        // 10,240,000 B
  float* Hb  = (float*)(ws + 20480000);                        // 10,240,000 B
  float* Y2  = (float*)(ws + 30720000);                        //  4,800,000 B
  float* zP  = (float*)(ws + 35520000);                        //  1,200,000 B
  float* zQ  = (float*)(ws + 36720000);                        //  1,200,000 B
  float* zout = (float*)d_out;

  // CSR by dst (reused by all 6 propagations)
  hipMemsetAsync(deg, 0, N_NODES * sizeof(int), stream);
  k_hist<<<(E + 255) / 256, 256, 0, stream>>>(edst, deg, E);
  k_scan<<<1, 1024, 0, stream>>>(deg, rowStart, cursor);
  k_scatter<<<(E + 255) / 256, 256, 0, stream>>>(esrc, edst, ew, cursor, srcS, wS, E);

  // GEMM1: Y = x @ [W1_0|W1_1|W1_2|W1_3]  (bf16 MFMA)
  k_cvt_x<<<(M_PAD * K_PAD) / 256, 256, 0, stream>>>(x, xb);
  k_cvt_w1<<<(N1 * K_PAD) / 256, 256, 0, stream>>>(W1, w1r);
  dim3 g1(M_PAD / BM, N1 / BN);
  k_gemm1<<<g1, 256, 0, stream>>>(xb, w1r, Y);

  // conv1 hops: h_pre = y0 + A(y1 + A(y2 + A*y3))
  k_prop128<<<N_NODES / 4, 256, 0, stream>>>(rowStart, srcS, wS, Y, N1, 3 * H_DIM, Y, N1, 2 * H_DIM, P);
  k_prop128<<<N_NODES / 4, 256, 0, stream>>>(rowStart, srcS, wS, P, H_DIM, 0, Y, N1, 1 * H_DIM, Q);
  k_prop128<<<N_NODES / 4, 256, 0, stream>>>(rowStart, srcS, wS, Q, H_DIM, 0, Y, N1, 0, P);

  k_bnrelu<<<(N_NODES * H_DIM) / 256, 256, 0, stream>>>(P, b1, gamma, beta, mmean, mvar, Hb);

  // GEMM2 + conv2 hops: z = u0 + A(u1 + A(u2 + A*u3)) + b2
  k_gemm2<<<N_NODES / 4, 256, 0, stream>>>(Hb, W2, Y2);
  k_prop15<<<N_NODES / 16, 256, 0, stream>>>(rowStart, srcS, wS, Y2, 60, 45, Y2, 60, 30, nullptr, zP);
  k_prop15<<<N_NODES / 16, 256, 0, stream>>>(rowStart, srcS, wS, zP, 15, 0, Y2, 60, 15, nullptr, zQ);
  k_prop15<<<N_NODES / 16, 256, 0, stream>>>(rowStart, srcS, wS, zQ, 15, 0, Y2, 60, 0, b2, zout);
}

// Round 2
// 640.729 us; speedup vs baseline: 1.2446x; 1.2446x over previous
//
#include <hip/hip_runtime.h>
#include <cstdint>
#include <cstddef>

#define N_NODES 20000
#define F_IN    2000
#define H_DIM   128
#define L_DIM   15
#define K_PAD   2048      // F padded for BK
#define M_PAD   20096     // 157 * 128
#define N1      512       // 4 hops * 128
#define BM      128
#define BN      128
#define BK      32

typedef __attribute__((ext_vector_type(4))) float f32x4;
typedef __attribute__((ext_vector_type(8))) short s16x8;
typedef __attribute__((ext_vector_type(8))) unsigned short u16x8;

__device__ __forceinline__ unsigned short f2bf(float f) {
  unsigned int u = __float_as_uint(f);
  u += 0x7fff + ((u >> 16) & 1);   // RNE
  return (unsigned short)(u >> 16);
}

// ---- x (fp32 [20000][2000]) -> bf16 padded [20096][2048]; 8 elems/thread ----
__global__ __launch_bounds__(256) void k_cvt_x(const float* __restrict__ x,
                                               unsigned short* __restrict__ xb) {
  unsigned int t = blockIdx.x * 256u + threadIdx.x;
  unsigned int row = t >> 8;               // 256 threads per 2048-col row
  unsigned int colB = (t & 255u) * 8u;
  u16x8 o = {0, 0, 0, 0, 0, 0, 0, 0};
  if (row < N_NODES && colB < F_IN) {      // F_IN % 8 == 0: all-or-none valid
    const float4 a = *(const float4*)(x + (size_t)row * F_IN + colB);
    const float4 b = *(const float4*)(x + (size_t)row * F_IN + colB + 4);
    o[0] = f2bf(a.x); o[1] = f2bf(a.y); o[2] = f2bf(a.z); o[3] = f2bf(a.w);
    o[4] = f2bf(b.x); o[5] = f2bf(b.y); o[6] = f2bf(b.z); o[7] = f2bf(b.w);
  }
  *(u16x8*)(xb + (size_t)t * 8) = o;       // row*2048+colB == t*8
}

// ---- W1 [8000][128] -> bf16 B^T [512][2048]; 8 elems/thread along k ----
__global__ __launch_bounds__(256) void k_cvt_w1(const float* __restrict__ W1,
                                                unsigned short* __restrict__ bt) {
  unsigned int t = blockIdx.x * 256u + threadIdx.x;
  unsigned int n = t >> 8;                 // output row (hop*128 + c)
  unsigned int kB = (t & 255u) * 8u;
  u16x8 o = {0, 0, 0, 0, 0, 0, 0, 0};
  if (kB < F_IN) {                         // F_IN % 8 == 0
    unsigned int hop = n >> 7, c = n & 127;
    const float* p = W1 + (size_t)(hop * F_IN + kB) * H_DIM + c;
#pragma unroll
    for (int q = 0; q < 8; ++q) o[q] = f2bf(p[(size_t)q * H_DIM]);
  }
  *(u16x8*)(bt + (size_t)t * 8) = o;
}

// ---- Y[20000][512] = xb @ w1r^T  (m97-style bf16 MFMA GEMM) ----
__global__ __launch_bounds__(256) void k_gemm1(const unsigned short* __restrict__ A,
                                               const unsigned short* __restrict__ B,
                                               float* __restrict__ C) {
  __shared__ unsigned short As[BM * BK];
  __shared__ unsigned short Bs[BN * BK];
  const int tid  = threadIdx.x;
  const int lane = tid & 63;
  const int wave = tid >> 6;
  const int wm = (wave >> 1) * 64;
  const int wn = (wave & 1) * 64;
  const int rowA0 = blockIdx.y * BM;   // grid = (4, 157): j-blocks dispatch-adjacent
  const int colB0 = blockIdx.x * BN;
  const int quad = lane >> 4;
  const int l15  = lane & 15;
  f32x4 acc[4][4] = {};

  for (int kt = 0; kt < K_PAD; kt += BK) {
#pragma unroll
    for (int r = 0; r < 2; ++r) {
      int c = r * 256 + tid;
      int row = c >> 2;
      int kc = (c & 3) * 8;
      const unsigned short* ga = A + (size_t)(rowA0 + row) * K_PAD + kt + kc;
      __builtin_amdgcn_global_load_lds((const __attribute__((address_space(1))) void*)ga,
                                       (__attribute__((address_space(3))) void*)(As + c * 8),
                                       16, 0, 0);
      const unsigned short* gb = B + (size_t)(colB0 + row) * K_PAD + kt + kc;
      __builtin_amdgcn_global_load_lds((const __attribute__((address_space(1))) void*)gb,
                                       (__attribute__((address_space(3))) void*)(Bs + c * 8),
                                       16, 0, 0);
    }
    __syncthreads();
    s16x8 af[4], bfr[4];
#pragma unroll
    for (int i = 0; i < 4; ++i)
      af[i] = *(const s16x8*)(As + (wm + i * 16 + l15) * BK + quad * 8);
#pragma unroll
    for (int j = 0; j < 4; ++j)
      bfr[j] = *(const s16x8*)(Bs + (wn + j * 16 + l15) * BK + quad * 8);
#pragma unroll
    for (int i = 0; i < 4; ++i)
#pragma unroll
      for (int j = 0; j < 4; ++j)
        acc[i][j] = __builtin_amdgcn_mfma_f32_16x16x32_bf16(af[i], bfr[j], acc[i][j], 0, 0, 0);
    __syncthreads();
  }

#pragma unroll
  for (int i = 0; i < 4; ++i) {
    int row0 = rowA0 + wm + i * 16 + quad * 4;
#pragma unroll
    for (int j = 0; j < 4; ++j) {
      int col = colB0 + wn + j * 16 + l15;
#pragma unroll
      for (int r = 0; r < 4; ++r) {
        int row = row0 + r;
        if (row < N_NODES) C[(size_t)row * N1 + col] = acc[i][j][r];
      }
    }
  }
}

// ---- CSR build: histogram (4 edges/thread), scan, scatter ----
__global__ __launch_bounds__(256) void k_hist(const int* __restrict__ dst,
                                              int* __restrict__ deg, int E) {
  int i = blockIdx.x * 256 + threadIdx.x;
  int e = i * 4;
  if (e + 4 <= E) {
    int4 d4 = *(const int4*)(dst + e);
    atomicAdd(&deg[d4.x], 1); atomicAdd(&deg[d4.y], 1);
    atomicAdd(&deg[d4.z], 1); atomicAdd(&deg[d4.w], 1);
  } else {
    for (; e < E; ++e) atomicAdd(&deg[dst[e]], 1);
  }
}

__global__ __launch_bounds__(1024) void k_scan(const int* __restrict__ deg,
                                               int* __restrict__ rowStart,
                                               int* __restrict__ cursor) {
  __shared__ int sums[1024];
  const int t = threadIdx.x;
  const int chunk = (N_NODES + 1023) / 1024;  // 20
  int lo = t * chunk;
  int hi = lo + chunk; if (hi > N_NODES) hi = N_NODES;
  int s = 0;
  for (int i = lo; i < hi; ++i) s += deg[i];
  sums[t] = s;
  __syncthreads();
  for (int off = 1; off < 1024; off <<= 1) {
    int v = sums[t];
    int u = (t >= off) ? sums[t - off] : 0;
    __syncthreads();
    sums[t] = v + u;
    __syncthreads();
  }
  int run = sums[t] - s;  // exclusive prefix
  for (int i = lo; i < hi; ++i) {
    rowStart[i] = run; cursor[i] = run; run += deg[i];
  }
  if (t == 1023) rowStart[N_NODES] = run;
}

__global__ __launch_bounds__(256) void k_scatter(const int* __restrict__ src,
                                                 const int* __restrict__ dst,
                                                 const float* __restrict__ w,
                                                 int* cursor,
                                                 int2* __restrict__ eSW, int E) {
  int e = blockIdx.x * 256 + threadIdx.x;
  if (e >= E) return;
  int p = atomicAdd(&cursor[dst[e]], 1);
  eSW[p] = make_int2(src[e], __float_as_int(w[e]));
}

// ---- pull-propagation, 128-wide: out[d] = addv[d] + sum w*in[src]; optional BN+ReLU ----
__global__ __launch_bounds__(256) void k_prop128(const int* __restrict__ rowStart,
    const int2* __restrict__ eSW,
    const float* __restrict__ in, int inStride, int inOff,
    const float* __restrict__ addv, int addStride, int addOff,
    float* __restrict__ out,
    const float* __restrict__ b1, const float* __restrict__ gamma,
    const float* __restrict__ beta, const float* __restrict__ mean,
    const float* __restrict__ var, int doBN) {
  const int lane = threadIdx.x & 63;
  const int d = blockIdx.x * 4 + (threadIdx.x >> 6);
  const int s0 = rowStart[d], s1 = rowStart[d + 1];
  const int c2 = lane * 2;
  float2 acc = make_float2(0.f, 0.f);
  int j = s0;
  for (; j + 4 <= s1; j += 4) {
    int2 e0 = eSW[j], e1 = eSW[j + 1], e2 = eSW[j + 2], e3 = eSW[j + 3];
    float2 v0 = *(const float2*)(in + (size_t)e0.x * inStride + inOff + c2);
    float2 v1 = *(const float2*)(in + (size_t)e1.x * inStride + inOff + c2);
    float2 v2 = *(const float2*)(in + (size_t)e2.x * inStride + inOff + c2);
    float2 v3 = *(const float2*)(in + (size_t)e3.x * inStride + inOff + c2);
    float w0 = __int_as_float(e0.y), w1 = __int_as_float(e1.y);
    float w2 = __int_as_float(e2.y), w3 = __int_as_float(e3.y);
    acc.x = fmaf(w0, v0.x, acc.x); acc.y = fmaf(w0, v0.y, acc.y);
    acc.x = fmaf(w1, v1.x, acc.x); acc.y = fmaf(w1, v1.y, acc.y);
    acc.x = fmaf(w2, v2.x, acc.x); acc.y = fmaf(w2, v2.y, acc.y);
    acc.x = fmaf(w3, v3.x, acc.x); acc.y = fmaf(w3, v3.y, acc.y);
  }
  for (; j < s1; ++j) {
    int2 e = eSW[j];
    float2 v = *(const float2*)(in + (size_t)e.x * inStride + inOff + c2);
    float w = __int_as_float(e.y);
    acc.x = fmaf(w, v.x, acc.x); acc.y = fmaf(w, v.y, acc.y);
  }
  float2 av = *(const float2*)(addv + (size_t)d * addStride + addOff + c2);
  float r0 = av.x + acc.x, r1 = av.y + acc.y;
  if (doBN) {
    float2 bb = *(const float2*)(b1 + c2);
    float2 gg = *(const float2*)(gamma + c2);
    float2 be = *(const float2*)(beta + c2);
    float2 mm = *(const float2*)(mean + c2);
    float2 vv = *(const float2*)(var + c2);
    r0 = (r0 + bb.x - mm.x) * rsqrtf(vv.x + 1e-3f) * gg.x + be.x;
    r1 = (r1 + bb.y - mm.y) * rsqrtf(vv.y + 1e-3f) * gg.y + be.y;
    r0 = r0 > 0.f ? r0 : 0.f;
    r1 = r1 > 0.f ? r1 : 0.f;
  }
  *(float2*)(out + (size_t)d * H_DIM + c2) = make_float2(r0, r1);
}

// ---- Y2[20000][60] = H @ W2 (4 hop-blocks of [128][15]); fp32 ----
__global__ __launch_bounds__(256) void k_gemm2(const float* __restrict__ Hh,
                                               const float* __restrict__ W2,
                                               float* __restrict__ Y2) {
  __shared__ float w2s[512 * 15];
  for (int i = threadIdx.x; i < 512 * 15; i += 256) w2s[i] = W2[i];
  __syncthreads();
  const int c = threadIdx.x & 63;
  const int d = blockIdx.x * 4 + (threadIdx.x >> 6);
  if (c >= 60 || d >= N_NODES) return;
  const int hop = c / 15, j = c % 15;
  const float4* hr4 = (const float4*)(Hh + (size_t)d * H_DIM);
  float acc = 0.f;
#pragma unroll 8
  for (int k4 = 0; k4 < 32; ++k4) {
    float4 h = hr4[k4];
    const float* wp = w2s + ((hop << 7) + k4 * 4) * 15 + j;
    acc = fmaf(h.x, wp[0],  acc);
    acc = fmaf(h.y, wp[15], acc);
    acc = fmaf(h.z, wp[30], acc);
    acc = fmaf(h.w, wp[45], acc);
  }
  Y2[(size_t)d * 60 + c] = acc;
}

// ---- pull-propagation, 15-wide ----
__global__ __launch_bounds__(256) void k_prop15(const int* __restrict__ rowStart,
    const int2* __restrict__ eSW,
    const float* __restrict__ in, int inStride, int inOff,
    const float* __restrict__ addv, int addStride, int addOff,
    const float* __restrict__ bias, float* __restrict__ out) {
  const int f = threadIdx.x & 15;
  const int d = blockIdx.x * 16 + (threadIdx.x >> 4);
  if (f >= 15) return;
  const int s0 = rowStart[d], s1 = rowStart[d + 1];
  float acc = 0.f;
  int j = s0;
  for (; j + 4 <= s1; j += 4) {
    int2 e0 = eSW[j], e1 = eSW[j + 1], e2 = eSW[j + 2], e3 = eSW[j + 3];
    float v0 = in[(size_t)e0.x * inStride + inOff + f];
    float v1 = in[(size_t)e1.x * inStride + inOff + f];
    float v2 = in[(size_t)e2.x * inStride + inOff + f];
    float v3 = in[(size_t)e3.x * inStride + inOff + f];
    acc = fmaf(__int_as_float(e0.y), v0, acc);
    acc = fmaf(__int_as_float(e1.y), v1, acc);
    acc = fmaf(__int_as_float(e2.y), v2, acc);
    acc = fmaf(__int_as_float(e3.y), v3, acc);
  }
  for (; j < s1; ++j) {
    int2 e = eSW[j];
    acc = fmaf(__int_as_float(e.y), in[(size_t)e.x * inStride + inOff + f], acc);
  }
  float b = bias ? bias[f] : 0.f;
  out[(size_t)d * 15 + f] = addv[(size_t)d * addStride + addOff + f] + acc + b;
}

extern "C" void kernel_launch(void* const* d_in, const int* in_sizes, int n_in,
                              void* d_out, int out_size, void* d_ws, size_t ws_size,
                              hipStream_t stream) {
  const float* x     = (const float*)d_in[0];
  const int*   esrc  = (const int*)d_in[1];
  const int*   edst  = (const int*)d_in[2];
  const float* ew    = (const float*)d_in[3];
  const float* W1    = (const float*)d_in[4];
  const float* b1    = (const float*)d_in[5];
  const float* gamma = (const float*)d_in[6];
  const float* beta  = (const float*)d_in[7];
  const float* mmean = (const float*)d_in[8];
  const float* mvar  = (const float*)d_in[9];
  const float* W2    = (const float*)d_in[10];
  const float* b2    = (const float*)d_in[11];
  const int E = in_sizes[1];
  char* ws = (char*)d_ws;

  // persistent region
  unsigned short* xb  = (unsigned short*)(ws);                 // 82,313,216 B
  unsigned short* w1r = (unsigned short*)(ws + 82313216);      //  2,097,152 B
  float* Y        = (float*)(ws + 84410368);                   // 40,960,000 B
  int*   deg      = (int*)(ws + 125370368);                    //     80,128 B
  int*   rowStart = (int*)(ws + 125450496);                    //     80,128 B
  int*   cursor   = (int*)(ws + 125530624);                    //     80,128 B
  int2*  eSW      = (int2*)(ws + 125610752);                   //  5,120,000 B
  // aliases over xb region (xb dead after k_gemm1)
  float* P   = (float*)(ws);                                   // 10,240,000 B
  float* Q   = (float*)(ws + 10240000);                        // 10,240,000 B
  float* Hb  = (float*)(ws + 20480000);                        // 10,240,000 B
  float* Y2  = (float*)(ws + 30720000);                        //  4,800,000 B
  float* zP  = (float*)(ws + 35520000);                        //  1,200,000 B
  float* zQ  = (float*)(ws + 36720000);                        //  1,200,000 B
  float* zout = (float*)d_out;

  // CSR by dst (reused by all 6 propagations)
  hipMemsetAsync(deg, 0, N_NODES * sizeof(int), stream);
  k_hist<<<(E / 4 + 255) / 256 + 1, 256, 0, stream>>>(edst, deg, E);
  k_scan<<<1, 1024, 0, stream>>>(deg, rowStart, cursor);
  k_scatter<<<(E + 255) / 256, 256, 0, stream>>>(esrc, edst, ew, cursor, eSW, E);

  // GEMM1: Y = x @ [W1_0|W1_1|W1_2|W1_3]  (bf16 MFMA)
  k_cvt_x<<<(M_PAD * K_PAD / 8) / 256, 256, 0, stream>>>(x, xb);
  k_cvt_w1<<<(N1 * K_PAD / 8) / 256, 256, 0, stream>>>(W1, w1r);
  dim3 g1(N1 / BN, M_PAD / BM);   // j-fastest for A-tile L2/L3 reuse
  k_gemm1<<<g1, 256, 0, stream>>>(xb, w1r, Y);

  // conv1 hops: h_pre = y0 + A(y1 + A(y2 + A*y3)); BN+ReLU fused into hop 3
  k_prop128<<<N_NODES / 4, 256, 0, stream>>>(rowStart, eSW, Y, N1, 3 * H_DIM, Y, N1, 2 * H_DIM, P,
                                             b1, gamma, beta, mmean, mvar, 0);
  k_prop128<<<N_NODES / 4, 256, 0, stream>>>(rowStart, eSW, P, H_DIM, 0, Y, N1, 1 * H_DIM, Q,
                                             b1, gamma, beta, mmean, mvar, 0);
  k_prop128<<<N_NODES / 4, 256, 0, stream>>>(rowStart, eSW, Q, H_DIM, 0, Y, N1, 0, Hb,
                                             b1, gamma, beta, mmean, mvar, 1);

  // GEMM2 + conv2 hops: z = u0 + A(u1 + A(u2 + A*u3)) + b2
  k_gemm2<<<N_NODES / 4, 256, 0, stream>>>(Hb, W2, Y2);
  k_prop15<<<N_NODES / 16, 256, 0, stream>>>(rowStart, eSW, Y2, 60, 45, Y2, 60, 30, nullptr, zP);
  k_prop15<<<N_NODES / 16, 256, 0, stream>>>(rowStart, eSW, zP, 15, 0, Y2, 60, 15, nullptr, zQ);
  k_prop15<<<N_NODES / 16, 256, 0, stream>>>(rowStart, eSW, zQ, 15, 0, Y2, 60, 0, b2, zout);
}

// Round 3
// 633.559 us; speedup vs baseline: 1.2587x; 1.0113x over previous
//
#include <hip/hip_runtime.h>
#include <cstdint>
#include <cstddef>

#define N_NODES 20000
#define F_IN    2000
#define H_DIM   128
#define L_DIM   15
#define K_PAD   2048      // F padded for BK
#define M_PAD   20096     // 157 * 128
#define N1      512       // 4 hops * 128
#define BM      128
#define BN      128
#define BK      32

typedef __attribute__((ext_vector_type(4))) float f32x4;
typedef __attribute__((ext_vector_type(8))) short s16x8;
typedef __attribute__((ext_vector_type(8))) unsigned short u16x8;

__device__ __forceinline__ unsigned short f2bf(float f) {
  unsigned int u = __float_as_uint(f);
  u += 0x7fff + ((u >> 16) & 1);   // RNE
  return (unsigned short)(u >> 16);
}

// ---- x (fp32 [20000][2000]) -> bf16 padded [20096][2048]; 8 elems/thread ----
__global__ __launch_bounds__(256) void k_cvt_x(const float* __restrict__ x,
                                               unsigned short* __restrict__ xb) {
  unsigned int t = blockIdx.x * 256u + threadIdx.x;
  unsigned int row = t >> 8;               // 256 threads per 2048-col row
  unsigned int colB = (t & 255u) * 8u;
  u16x8 o = {0, 0, 0, 0, 0, 0, 0, 0};
  if (row < N_NODES && colB < F_IN) {      // F_IN % 8 == 0: all-or-none valid
    const float4 a = *(const float4*)(x + (size_t)row * F_IN + colB);
    const float4 b = *(const float4*)(x + (size_t)row * F_IN + colB + 4);
    o[0] = f2bf(a.x); o[1] = f2bf(a.y); o[2] = f2bf(a.z); o[3] = f2bf(a.w);
    o[4] = f2bf(b.x); o[5] = f2bf(b.y); o[6] = f2bf(b.z); o[7] = f2bf(b.w);
  }
  *(u16x8*)(xb + (size_t)t * 8) = o;       // row*2048+colB == t*8
}

// ---- W1 [8000][128] -> bf16 B^T [512][2048] via coalesced read + LDS transpose ----
// grid: 4 hops * 32 k-tiles = 128 blocks; tile = 64 k x 128 c
__global__ __launch_bounds__(256) void k_cvt_w1(const float* __restrict__ W1,
                                                unsigned short* __restrict__ bt) {
  __shared__ unsigned short tile[128 * 67];   // [c][r], stride 67 -> ~2-way banks
  const int hop = blockIdx.x >> 5;
  const int k0  = (blockIdx.x & 31) * 64;
  const int t = threadIdx.x;
#pragma unroll
  for (int it = 0; it < 8; ++it) {
    int f4 = it * 256 + t;                    // 0..2047 float4 chunks
    int r  = f4 >> 5;                         // k row 0..63
    int c4 = f4 & 31;
    int k = k0 + r;
    float4 v = make_float4(0.f, 0.f, 0.f, 0.f);
    if (k < F_IN) v = *(const float4*)(W1 + (size_t)(hop * F_IN + k) * H_DIM + c4 * 4);
    tile[(c4 * 4 + 0) * 67 + r] = f2bf(v.x);
    tile[(c4 * 4 + 1) * 67 + r] = f2bf(v.y);
    tile[(c4 * 4 + 2) * 67 + r] = f2bf(v.z);
    tile[(c4 * 4 + 3) * 67 + r] = f2bf(v.w);
  }
  __syncthreads();
  const int c = t >> 1, kh = (t & 1) * 32;
  unsigned short* dst = bt + (size_t)(hop * 128 + c) * K_PAD + k0 + kh;
  const unsigned short* srcp = tile + c * 67 + kh;
#pragma unroll
  for (int q = 0; q < 4; ++q) {
    u16x8 o;
#pragma unroll
    for (int e = 0; e < 8; ++e) o[e] = srcp[q * 8 + e];
    *(u16x8*)(dst + q * 8) = o;
  }
}

// ---- Y[20000][512] = xb @ w1r^T (bf16 MFMA), XCD-affinity swizzled grid ----
// grid = 640 1D blocks. xcd = b&7; all 4 j-blocks of tile i share b mod 8
// (same XCD under round-robin) and launch within 32 ids -> A-tile L2 reuse.
__global__ __launch_bounds__(256) void k_gemm1(const unsigned short* __restrict__ A,
                                               const unsigned short* __restrict__ B,
                                               float* __restrict__ C) {
  __shared__ unsigned short As[BM * BK];
  __shared__ unsigned short Bs[BN * BK];
  const int b = blockIdx.x;
  const int i_tile = (b & 7) + 8 * (b >> 5);
  const int j_tile = (b >> 3) & 3;
  if (i_tile >= M_PAD / BM) return;
  const int rowA0 = i_tile * BM;
  const int colB0 = j_tile * BN;
  const int tid  = threadIdx.x;
  const int lane = tid & 63;
  const int wave = tid >> 6;
  const int wm = (wave >> 1) * 64;
  const int wn = (wave & 1) * 64;
  const int quad = lane >> 4;
  const int l15  = lane & 15;
  f32x4 acc[4][4] = {};

  for (int kt = 0; kt < K_PAD; kt += BK) {
#pragma unroll
    for (int r = 0; r < 2; ++r) {
      int c = r * 256 + tid;
      int row = c >> 2;
      int kc = (c & 3) * 8;
      const unsigned short* ga = A + (size_t)(rowA0 + row) * K_PAD + kt + kc;
      __builtin_amdgcn_global_load_lds((const __attribute__((address_space(1))) void*)ga,
                                       (__attribute__((address_space(3))) void*)(As + c * 8),
                                       16, 0, 0);
      const unsigned short* gb = B + (size_t)(colB0 + row) * K_PAD + kt + kc;
      __builtin_amdgcn_global_load_lds((const __attribute__((address_space(1))) void*)gb,
                                       (__attribute__((address_space(3))) void*)(Bs + c * 8),
                                       16, 0, 0);
    }
    __syncthreads();
    s16x8 af[4], bfr[4];
#pragma unroll
    for (int i = 0; i < 4; ++i)
      af[i] = *(const s16x8*)(As + (wm + i * 16 + l15) * BK + quad * 8);
#pragma unroll
    for (int j = 0; j < 4; ++j)
      bfr[j] = *(const s16x8*)(Bs + (wn + j * 16 + l15) * BK + quad * 8);
#pragma unroll
    for (int i = 0; i < 4; ++i)
#pragma unroll
      for (int j = 0; j < 4; ++j)
        acc[i][j] = __builtin_amdgcn_mfma_f32_16x16x32_bf16(af[i], bfr[j], acc[i][j], 0, 0, 0);
    __syncthreads();
  }

#pragma unroll
  for (int i = 0; i < 4; ++i) {
    int row0 = rowA0 + wm + i * 16 + quad * 4;
#pragma unroll
    for (int j = 0; j < 4; ++j) {
      int col = colB0 + wn + j * 16 + l15;
#pragma unroll
      for (int r = 0; r < 4; ++r) {
        int row = row0 + r;
        if (row < N_NODES) C[(size_t)row * N1 + col] = acc[i][j][r];
      }
    }
  }
}

// ---- CSR build: histogram (4 edges/thread), scan, scatter ----
__global__ __launch_bounds__(256) void k_hist(const int* __restrict__ dst,
                                              int* __restrict__ deg, int E) {
  int i = blockIdx.x * 256 + threadIdx.x;
  int e = i * 4;
  if (e + 4 <= E) {
    int4 d4 = *(const int4*)(dst + e);
    atomicAdd(&deg[d4.x], 1); atomicAdd(&deg[d4.y], 1);
    atomicAdd(&deg[d4.z], 1); atomicAdd(&deg[d4.w], 1);
  } else {
    for (; e < E; ++e) atomicAdd(&deg[dst[e]], 1);
  }
}

__global__ __launch_bounds__(1024) void k_scan(const int* __restrict__ deg,
                                               int* __restrict__ rowStart,
                                               int* __restrict__ cursor) {
  __shared__ int sums[1024];
  const int t = threadIdx.x;
  const int chunk = (N_NODES + 1023) / 1024;  // 20
  int lo = t * chunk;
  int hi = lo + chunk; if (hi > N_NODES) hi = N_NODES;
  int s = 0;
  for (int i = lo; i < hi; ++i) s += deg[i];
  sums[t] = s;
  __syncthreads();
  for (int off = 1; off < 1024; off <<= 1) {
    int v = sums[t];
    int u = (t >= off) ? sums[t - off] : 0;
    __syncthreads();
    sums[t] = v + u;
    __syncthreads();
  }
  int run = sums[t] - s;  // exclusive prefix
  for (int i = lo; i < hi; ++i) {
    rowStart[i] = run; cursor[i] = run; run += deg[i];
  }
  if (t == 1023) rowStart[N_NODES] = run;
}

__global__ __launch_bounds__(256) void k_scatter(const int* __restrict__ src,
                                                 const int* __restrict__ dst,
                                                 const float* __restrict__ w,
                                                 int* cursor,
                                                 int2* __restrict__ eSW, int E) {
  int e = blockIdx.x * 256 + threadIdx.x;
  if (e >= E) return;
  int p = atomicAdd(&cursor[dst[e]], 1);
  eSW[p] = make_int2(src[e], __float_as_int(w[e]));
}

// ---- pull-propagation, 128-wide: out[d] = addv[d] + sum w*in[src]; optional BN+ReLU ----
__global__ __launch_bounds__(256) void k_prop128(const int* __restrict__ rowStart,
    const int2* __restrict__ eSW,
    const float* __restrict__ in, int inStride, int inOff,
    const float* __restrict__ addv, int addStride, int addOff,
    float* __restrict__ out,
    const float* __restrict__ b1, const float* __restrict__ gamma,
    const float* __restrict__ beta, const float* __restrict__ mean,
    const float* __restrict__ var, int doBN) {
  const int lane = threadIdx.x & 63;
  const int d = blockIdx.x * 4 + (threadIdx.x >> 6);
  const int s0 = rowStart[d], s1 = rowStart[d + 1];
  const int c2 = lane * 2;
  float2 acc = make_float2(0.f, 0.f);
  int j = s0;
  for (; j + 8 <= s1; j += 8) {
    int2 e0 = eSW[j],     e1 = eSW[j + 1], e2 = eSW[j + 2], e3 = eSW[j + 3];
    int2 e4 = eSW[j + 4], e5 = eSW[j + 5], e6 = eSW[j + 6], e7 = eSW[j + 7];
    float2 v0 = *(const float2*)(in + (size_t)e0.x * inStride + inOff + c2);
    float2 v1 = *(const float2*)(in + (size_t)e1.x * inStride + inOff + c2);
    float2 v2 = *(const float2*)(in + (size_t)e2.x * inStride + inOff + c2);
    float2 v3 = *(const float2*)(in + (size_t)e3.x * inStride + inOff + c2);
    float2 v4 = *(const float2*)(in + (size_t)e4.x * inStride + inOff + c2);
    float2 v5 = *(const float2*)(in + (size_t)e5.x * inStride + inOff + c2);
    float2 v6 = *(const float2*)(in + (size_t)e6.x * inStride + inOff + c2);
    float2 v7 = *(const float2*)(in + (size_t)e7.x * inStride + inOff + c2);
    float w0 = __int_as_float(e0.y), w1 = __int_as_float(e1.y);
    float w2 = __int_as_float(e2.y), w3 = __int_as_float(e3.y);
    float w4 = __int_as_float(e4.y), w5 = __int_as_float(e5.y);
    float w6 = __int_as_float(e6.y), w7 = __int_as_float(e7.y);
    acc.x = fmaf(w0, v0.x, acc.x); acc.y = fmaf(w0, v0.y, acc.y);
    acc.x = fmaf(w1, v1.x, acc.x); acc.y = fmaf(w1, v1.y, acc.y);
    acc.x = fmaf(w2, v2.x, acc.x); acc.y = fmaf(w2, v2.y, acc.y);
    acc.x = fmaf(w3, v3.x, acc.x); acc.y = fmaf(w3, v3.y, acc.y);
    acc.x = fmaf(w4, v4.x, acc.x); acc.y = fmaf(w4, v4.y, acc.y);
    acc.x = fmaf(w5, v5.x, acc.x); acc.y = fmaf(w5, v5.y, acc.y);
    acc.x = fmaf(w6, v6.x, acc.x); acc.y = fmaf(w6, v6.y, acc.y);
    acc.x = fmaf(w7, v7.x, acc.x); acc.y = fmaf(w7, v7.y, acc.y);
  }
  for (; j + 4 <= s1; j += 4) {
    int2 e0 = eSW[j], e1 = eSW[j + 1], e2 = eSW[j + 2], e3 = eSW[j + 3];
    float2 v0 = *(const float2*)(in + (size_t)e0.x * inStride + inOff + c2);
    float2 v1 = *(const float2*)(in + (size_t)e1.x * inStride + inOff + c2);
    float2 v2 = *(const float2*)(in + (size_t)e2.x * inStride + inOff + c2);
    float2 v3 = *(const float2*)(in + (size_t)e3.x * inStride + inOff + c2);
    float w0 = __int_as_float(e0.y), w1 = __int_as_float(e1.y);
    float w2 = __int_as_float(e2.y), w3 = __int_as_float(e3.y);
    acc.x = fmaf(w0, v0.x, acc.x); acc.y = fmaf(w0, v0.y, acc.y);
    acc.x = fmaf(w1, v1.x, acc.x); acc.y = fmaf(w1, v1.y, acc.y);
    acc.x = fmaf(w2, v2.x, acc.x); acc.y = fmaf(w2, v2.y, acc.y);
    acc.x = fmaf(w3, v3.x, acc.x); acc.y = fmaf(w3, v3.y, acc.y);
  }
  for (; j < s1; ++j) {
    int2 e = eSW[j];
    float2 v = *(const float2*)(in + (size_t)e.x * inStride + inOff + c2);
    float w = __int_as_float(e.y);
    acc.x = fmaf(w, v.x, acc.x); acc.y = fmaf(w, v.y, acc.y);
  }
  float2 av = *(const float2*)(addv + (size_t)d * addStride + addOff + c2);
  float r0 = av.x + acc.x, r1 = av.y + acc.y;
  if (doBN) {
    float2 bb = *(const float2*)(b1 + c2);
    float2 gg = *(const float2*)(gamma + c2);
    float2 be = *(const float2*)(beta + c2);
    float2 mm = *(const float2*)(mean + c2);
    float2 vv = *(const float2*)(var + c2);
    r0 = (r0 + bb.x - mm.x) * rsqrtf(vv.x + 1e-3f) * gg.x + be.x;
    r1 = (r1 + bb.y - mm.y) * rsqrtf(vv.y + 1e-3f) * gg.y + be.y;
    r0 = r0 > 0.f ? r0 : 0.f;
    r1 = r1 > 0.f ? r1 : 0.f;
  }
  *(float2*)(out + (size_t)d * H_DIM + c2) = make_float2(r0, r1);
}

// ---- Y2[20000][60] = H @ W2 (4 hop-blocks of [128][15]); fp32 ----
__global__ __launch_bounds__(256) void k_gemm2(const float* __restrict__ Hh,
                                               const float* __restrict__ W2,
                                               float* __restrict__ Y2) {
  __shared__ float w2s[512 * 15];
  for (int i = threadIdx.x; i < 512 * 15; i += 256) w2s[i] = W2[i];
  __syncthreads();
  const int c = threadIdx.x & 63;
  const int d = blockIdx.x * 4 + (threadIdx.x >> 6);
  if (c >= 60 || d >= N_NODES) return;
  const int hop = c / 15, j = c % 15;
  const float4* hr4 = (const float4*)(Hh + (size_t)d * H_DIM);
  float acc = 0.f;
#pragma unroll 8
  for (int k4 = 0; k4 < 32; ++k4) {
    float4 h = hr4[k4];
    const float* wp = w2s + ((hop << 7) + k4 * 4) * 15 + j;
    acc = fmaf(h.x, wp[0],  acc);
    acc = fmaf(h.y, wp[15], acc);
    acc = fmaf(h.z, wp[30], acc);
    acc = fmaf(h.w, wp[45], acc);
  }
  Y2[(size_t)d * 60 + c] = acc;
}

// ---- pull-propagation, 15-wide ----
__global__ __launch_bounds__(256) void k_prop15(const int* __restrict__ rowStart,
    const int2* __restrict__ eSW,
    const float* __restrict__ in, int inStride, int inOff,
    const float* __restrict__ addv, int addStride, int addOff,
    const float* __restrict__ bias, float* __restrict__ out) {
  const int f = threadIdx.x & 15;
  const int d = blockIdx.x * 16 + (threadIdx.x >> 4);
  if (f >= 15) return;
  const int s0 = rowStart[d], s1 = rowStart[d + 1];
  float acc = 0.f;
  int j = s0;
  for (; j + 4 <= s1; j += 4) {
    int2 e0 = eSW[j], e1 = eSW[j + 1], e2 = eSW[j + 2], e3 = eSW[j + 3];
    float v0 = in[(size_t)e0.x * inStride + inOff + f];
    float v1 = in[(size_t)e1.x * inStride + inOff + f];
    float v2 = in[(size_t)e2.x * inStride + inOff + f];
    float v3 = in[(size_t)e3.x * inStride + inOff + f];
    acc = fmaf(__int_as_float(e0.y), v0, acc);
    acc = fmaf(__int_as_float(e1.y), v1, acc);
    acc = fmaf(__int_as_float(e2.y), v2, acc);
    acc = fmaf(__int_as_float(e3.y), v3, acc);
  }
  for (; j < s1; ++j) {
    int2 e = eSW[j];
    acc = fmaf(__int_as_float(e.y), in[(size_t)e.x * inStride + inOff + f], acc);
  }
  float b = bias ? bias[f] : 0.f;
  out[(size_t)d * 15 + f] = addv[(size_t)d * addStride + addOff + f] + acc + b;
}

extern "C" void kernel_launch(void* const* d_in, const int* in_sizes, int n_in,
                              void* d_out, int out_size, void* d_ws, size_t ws_size,
                              hipStream_t stream) {
  const float* x     = (const float*)d_in[0];
  const int*   esrc  = (const int*)d_in[1];
  const int*   edst  = (const int*)d_in[2];
  const float* ew    = (const float*)d_in[3];
  const float* W1    = (const float*)d_in[4];
  const float* b1    = (const float*)d_in[5];
  const float* gamma = (const float*)d_in[6];
  const float* beta  = (const float*)d_in[7];
  const float* mmean = (const float*)d_in[8];
  const float* mvar  = (const float*)d_in[9];
  const float* W2    = (const float*)d_in[10];
  const float* b2    = (const float*)d_in[11];
  const int E = in_sizes[1];
  char* ws = (char*)d_ws;

  // persistent region
  unsigned short* xb  = (unsigned short*)(ws);                 // 82,313,216 B
  unsigned short* w1r = (unsigned short*)(ws + 82313216);      //  2,097,152 B
  float* Y        = (float*)(ws + 84410368);                   // 40,960,000 B
  int*   deg      = (int*)(ws + 125370368);                    //     80,128 B
  int*   rowStart = (int*)(ws + 125450496);                    //     80,128 B
  int*   cursor   = (int*)(ws + 125530624);                    //     80,128 B
  int2*  eSW      = (int2*)(ws + 125610752);                   //  5,120,000 B
  // aliases over xb region (xb dead after k_gemm1)
  float* P   = (float*)(ws);                                   // 10,240,000 B
  float* Q   = (float*)(ws + 10240000);                        // 10,240,000 B
  float* Hb  = (float*)(ws + 20480000);                        // 10,240,000 B
  float* Y2  = (float*)(ws + 30720000);                        //  4,800,000 B
  float* zP  = (float*)(ws + 35520000);                        //  1,200,000 B
  float* zQ  = (float*)(ws + 36720000);                        //  1,200,000 B
  float* zout = (float*)d_out;

  // CSR by dst (reused by all 6 propagations)
  hipMemsetAsync(deg, 0, N_NODES * sizeof(int), stream);
  k_hist<<<(E / 4 + 255) / 256 + 1, 256, 0, stream>>>(edst, deg, E);
  k_scan<<<1, 1024, 0, stream>>>(deg, rowStart, cursor);
  k_scatter<<<(E + 255) / 256, 256, 0, stream>>>(esrc, edst, ew, cursor, eSW, E);

  // GEMM1: Y = x @ [W1_0|W1_1|W1_2|W1_3]  (bf16 MFMA)
  k_cvt_x<<<(M_PAD * K_PAD / 8) / 256, 256, 0, stream>>>(x, xb);
  k_cvt_w1<<<128, 256, 0, stream>>>(W1, w1r);
  k_gemm1<<<640, 256, 0, stream>>>(xb, w1r, Y);   // XCD-affinity swizzle inside

  // conv1 hops: h_pre = y0 + A(y1 + A(y2 + A*y3)); BN+ReLU fused into hop 3
  k_prop128<<<N_NODES / 4, 256, 0, stream>>>(rowStart, eSW, Y, N1, 3 * H_DIM, Y, N1, 2 * H_DIM, P,
                                             b1, gamma, beta, mmean, mvar, 0);
  k_prop128<<<N_NODES / 4, 256, 0, stream>>>(rowStart, eSW, P, H_DIM, 0, Y, N1, 1 * H_DIM, Q,
                                             b1, gamma, beta, mmean, mvar, 0);
  k_prop128<<<N_NODES / 4, 256, 0, stream>>>(rowStart, eSW, Q, H_DIM, 0, Y, N1, 0, Hb,
                                             b1, gamma, beta, mmean, mvar, 1);

  // GEMM2 + conv2 hops: z = u0 + A(u1 + A(u2 + A*u3)) + b2
  k_gemm2<<<N_NODES / 4, 256, 0, stream>>>(Hb, W2, Y2);
  k_prop15<<<N_NODES / 16, 256, 0, stream>>>(rowStart, eSW, Y2, 60, 45, Y2, 60, 30, nullptr, zP);
  k_prop15<<<N_NODES / 16, 256, 0, stream>>>(rowStart, eSW, zP, 15, 0, Y2, 60, 15, nullptr, zQ);
  k_prop15<<<N_NODES / 16, 256, 0, stream>>>(rowStart, eSW, zQ, 15, 0, Y2, 60, 0, b2, zout);
}